// Round 6
// baseline (218.966 us; speedup 1.0000x reference)
//
#include <hip/hip_runtime.h>

// nonlocal_channel_similarity: B=16, C=256, H=W=64 (N=HW=4096)
//   k_gram : blocks 0..511  : per (ks,b) upper-triangle 16x16 sub-tiles of the
//            partial Gram over K-chunk 128; x read from HBM exactly once.
//            Compact slab (136 tiles * 512 B), coalesced uint2 stores.
//            Row-sum partials -> Spart (plain stores, no atomics).
//            blocks 512..639: Q = gw@Pw (bf16) + E = gw.pb  (overlapped -
//            independent of gram output, runs in its memory shadow).
//   k_fuse2: blocks 0..543: reduce 32 slabs -> bf16 Gh (straight + mirror)
//            blocks 544..575: u = Tw s, v = Pw s   (s = sum of Spart)
//            blocks 576..591: out[b,:] = db  (init for k_p atomics)
//   k_p    : P'' = Gh Qh^T via MFMA; fused term = Tw-contraction + bias +
//            relu; epilogue rank-16 update atomicAdd into out (k_out fused).

#define CC  256
#define NB  16
#define HWN 4096
#define KSPLIT 32
#define NPAIR 136   // 16x16 sub-tile pairs (w,ct), ct >= w

typedef __attribute__((ext_vector_type(4))) float f32x4;
typedef __attribute__((ext_vector_type(8))) short bf16x8;

__device__ inline unsigned short f2bf(float f) {
  unsigned u = __float_as_uint(f);
  u += 0x7fff + ((u >> 16) & 1);   // round-to-nearest-even
  return (unsigned short)(u >> 16);
}
__device__ inline float bf2f(unsigned u) { return __uint_as_float(u << 16); }

// ---------------- Gram partials + row-sum partials + Q/E --------------------
// 1D grid 640 blocks, 1024 threads = 16 waves, LDS 64 KB -> 2 blocks/CU.
// Gram blocks: wave w: A-rows [16w,16w+16), B-tiles ct = w..15 (G symmetric).
// LDS 256x64 bf16 double-buffered, XOR-granule swizzle.
__global__ __launch_bounds__(1024, 8) void k_gram(const float* __restrict__ x,
                                                  unsigned short* __restrict__ slab,
                                                  float* __restrict__ Spart,
                                                  const float* __restrict__ gw,
                                                  const float* __restrict__ pw,
                                                  const float* __restrict__ pb,
                                                  unsigned short* __restrict__ Qh,
                                                  float* __restrict__ E) {
  __shared__ __align__(16) unsigned short As[2][256 * 64];
  const int blk = blockIdx.x, tid = threadIdx.x;

  if (blk >= 512) {
    // ---- Q rows (4 per block) + E: independent of gram, overlapped ----
    const int sub = tid >> 8, t = tid & 255;
    const int rj = (blk - 512) * 4 + sub;
    float* smg = (float*)As + sub * 512;
    smg[t] = gw[rj * 256 + t];
    __syncthreads();
    float q = 0.f;
    for (int p = 0; p < 256; ++p) q += smg[p] * pw[p * 256 + t];
    Qh[rj * 256 + t] = f2bf(q);
    smg[256 + t] = smg[t] * pb[t];
    __syncthreads();
    for (int s = 128; s > 0; s >>= 1) {
      if (t < s) smg[256 + t] += smg[256 + t + s];
      __syncthreads();
    }
    if (t == 0) E[rj] = smg[256];
    return;
  }

  const int ks = blk >> 4, b = blk & 15;
  const float* xb = x + (size_t)b * CC * HWN;

  const int w = tid >> 6, lane = tid & 63;
  const int quad = lane >> 4, m15 = lane & 15;
  const int srow = tid >> 4;                 // 0..63
  const int scol = (tid & 15) << 2;          // 0..60
  const int sg = scol >> 3, so = scol & 7;

  f32x4 acc[16];
  #pragma unroll
  for (int i = 0; i < 16; ++i) acc[i] = (f32x4){0.f, 0.f, 0.f, 0.f};
  float rs[4] = {0.f, 0.f, 0.f, 0.f};

  const int k0 = ks * 128;
  float4 ld[4];
  #pragma unroll
  for (int p = 0; p < 4; ++p)
    ld[p] = *(const float4*)(xb + (size_t)(p * 64 + srow) * HWN + k0 + scol);
  #pragma unroll
  for (int p = 0; p < 4; ++p) {
    const int row = p * 64 + srow;
    rs[p] += ld[p].x + ld[p].y + ld[p].z + ld[p].w;
    *(ushort4*)&As[0][row * 64 + ((sg ^ (row & 7)) << 3) + so] =
        make_ushort4(f2bf(ld[p].x), f2bf(ld[p].y), f2bf(ld[p].z), f2bf(ld[p].w));
  }
  __syncthreads();

  #pragma unroll
  for (int i = 0; i < 2; ++i) {
    if (i < 1) {
      #pragma unroll
      for (int p = 0; p < 4; ++p)
        ld[p] = *(const float4*)(xb + (size_t)(p * 64 + srow) * HWN + k0 + 64 + scol);
    }
    const int rowa = 16 * w + m15;
    #pragma unroll
    for (int kkg = 0; kkg < 8; kkg += 4) {
      const int ga = (kkg + quad) ^ (m15 & 7);
      bf16x8 af = *(const bf16x8*)&As[i][rowa * 64 + ga * 8];
      #pragma unroll
      for (int ct = 0; ct < 16; ++ct) {
        if (ct < w) continue;   // wave-uniform triangle skip
        bf16x8 bfr = *(const bf16x8*)&As[i][(16 * ct + m15) * 64 + ga * 8];
        acc[ct] = __builtin_amdgcn_mfma_f32_16x16x32_bf16(af, bfr, acc[ct], 0, 0, 0);
      }
    }
    if (i < 1) {
      #pragma unroll
      for (int p = 0; p < 4; ++p) {
        const int row = p * 64 + srow;
        rs[p] += ld[p].x + ld[p].y + ld[p].z + ld[p].w;
        *(ushort4*)&As[1][row * 64 + ((sg ^ (row & 7)) << 3) + so] =
            make_ushort4(f2bf(ld[p].x), f2bf(ld[p].y), f2bf(ld[p].z), f2bf(ld[p].w));
      }
    }
    __syncthreads();
  }

  // compact slab: pair (w,ct) -> 512 B tile; lane writes its 4 regs as uint2.
  const int off_w = 16 * w - (w * (w - 1)) / 2;
  unsigned short* sbase = slab + ((size_t)(ks * 16 + b) * NPAIR) * 256;
  #pragma unroll
  for (int ct = 0; ct < 16; ++ct) {
    if (ct < w) continue;
    const int pid = off_w + (ct - w);
    uint2 ov;
    ov.x = (unsigned)f2bf(acc[ct][0]) | ((unsigned)f2bf(acc[ct][1]) << 16);
    ov.y = (unsigned)f2bf(acc[ct][2]) | ((unsigned)f2bf(acc[ct][3]) << 16);
    *(uint2*)(sbase + pid * 256 + lane * 4) = ov;
  }

  #pragma unroll
  for (int p = 0; p < 4; ++p) {
    float v = rs[p];
    v += __shfl_xor(v, 1);
    v += __shfl_xor(v, 2);
    v += __shfl_xor(v, 4);
    v += __shfl_xor(v, 8);
    if ((tid & 15) == 0)
      Spart[(ks * 16 + b) * 256 + p * 64 + srow] = v;
  }
}

// ---------------- fused middle: reduce + u/v + out-init ---------------------
__global__ __launch_bounds__(256) void k_fuse2(const unsigned short* __restrict__ slab,
                                               const float* __restrict__ Spart,
                                               const float* __restrict__ pw,
                                               const float* __restrict__ tw,
                                               const float* __restrict__ db,
                                               unsigned short* __restrict__ Gh,
                                               float* __restrict__ U,
                                               float* __restrict__ V,
                                               float* __restrict__ out) {
  const int blk = blockIdx.x, tid = threadIdx.x;
  if (blk < 544) {
    // slab reduce: thread <-> (b, pair, lane)
    const int t = blk * 256 + tid;          // 0..139263
    const int b = t / 8704;
    const int rem = t % 8704;
    const int pid0 = rem >> 6, lane = rem & 63;
    int w = 0, p = pid0;
    while (p >= 16 - w) { p -= 16 - w; ++w; }
    const int ct = w + p;
    const int quad = lane >> 4, m15 = lane & 15;
    float s[4] = {0.f, 0.f, 0.f, 0.f};
    const unsigned short* sp = slab + (size_t)(b * NPAIR + pid0) * 256 + lane * 4;
    #pragma unroll
    for (int ks = 0; ks < KSPLIT; ++ks) {
      const uint2 v = *(const uint2*)(sp + (size_t)ks * 16 * NPAIR * 256);
      s[0] += bf2f(v.x & 0xffffu); s[1] += bf2f(v.x >> 16);
      s[2] += bf2f(v.y & 0xffffu); s[3] += bf2f(v.y >> 16);
    }
    unsigned short h[4];
    #pragma unroll
    for (int r = 0; r < 4; ++r) h[r] = f2bf(s[r]);
    unsigned short* Gb = Gh + ((size_t)b << 16);
    const int rb = 16 * w + quad * 4;
    const int col = 16 * ct + m15;
    #pragma unroll
    for (int r = 0; r < 4; ++r) Gb[(rb + r) * 256 + col] = h[r];
    // mirror (exact; diagonal overlap writes identical values)
    uint2 mv;
    mv.x = (unsigned)h[0] | ((unsigned)h[1] << 16);
    mv.y = (unsigned)h[2] | ((unsigned)h[3] << 16);
    *(uint2*)(Gb + col * 256 + rb) = mv;
  } else if (blk < 576) {
    // u or v for batch b
    const int m = blk - 544;
    const int b = m & 15, mat = m >> 4;
    const float* Wm = mat ? pw : tw;
    float* outp = mat ? V : U;
    __shared__ float sm[256];
    float sv = 0.f;
    #pragma unroll
    for (int ks = 0; ks < KSPLIT; ++ks)
      sv += Spart[(ks * 16 + b) * 256 + tid];
    sm[tid] = sv;
    __syncthreads();
    const int l = tid & 15, oh = tid >> 4;
    #pragma unroll
    for (int oc = 0; oc < 16; ++oc) {
      const int o = oc * 16 + oh;
      float a = 0.f;
      #pragma unroll
      for (int j = 0; j < 16; ++j)
        a += Wm[o * 256 + l * 16 + j] * sm[l * 16 + j];
      a += __shfl_xor(a, 1);
      a += __shfl_xor(a, 2);
      a += __shfl_xor(a, 4);
      a += __shfl_xor(a, 8);
      if (l == 0) outp[b * 256 + o] = a;
    }
  } else {
    // out init: out[b,:] = db
    const int b = blk - 576;
    out[b * 256 + tid] = db[tid];
  }
}

// ---------------- P'' = Gh Qh^T + fused epilogue (bias/relu + out-update) ---
// grid (32 rj-tiles of 16, 16 b) = 512 blocks (2/CU), 256 thr / 4 waves.
// Wave w: m-rows [64w,64w+64). K = 256. Direct bf16 global loads (L2-hot).
// Epilogue: g (16 values) -> rank-16 atomic update of out[b,:].
__global__ __launch_bounds__(256) void k_p(const unsigned short* __restrict__ Gh,
                                           const unsigned short* __restrict__ Qh,
                                           const float* __restrict__ tw,
                                           const float* __restrict__ gw,
                                           const float* __restrict__ U,
                                           const float* __restrict__ V,
                                           const float* __restrict__ E,
                                           const float* __restrict__ tb,
                                           const float* __restrict__ gb,
                                           const float* __restrict__ dw,
                                           float* __restrict__ out) {
  const int rjt = blockIdx.x, b = blockIdx.y;
  const int rj0 = rjt * 16;
  const int tid = threadIdx.x, w = tid >> 6, lane = tid & 63;
  const int quad = lane >> 4, m15 = lane & 15;
  const unsigned short* Gb = Gh + ((size_t)b << 16);

  f32x4 acc[4];
  #pragma unroll
  for (int mt = 0; mt < 4; ++mt) acc[mt] = (f32x4){0.f, 0.f, 0.f, 0.f};

  #pragma unroll
  for (int s = 0; s < 8; ++s) {
    const int kb = s * 32 + quad * 8;
    bf16x8 bq = *(const bf16x8*)(Qh + (rj0 + m15) * 256 + kb);
    #pragma unroll
    for (int mt = 0; mt < 4; ++mt) {
      bf16x8 ag = *(const bf16x8*)(Gb + (64 * w + 16 * mt + m15) * 256 + kb);
      acc[mt] = __builtin_amdgcn_mfma_f32_16x16x32_bf16(ag, bq, acc[mt], 0, 0, 0);
    }
  }

  // term[rj] = sum_c P''[c,rj]*Tw[r,c]; C/D: col = m15, row = quad*4+reg
  __shared__ float sred[16 * 4];
  __shared__ float sred2[16];
  __shared__ float gsh[16];
  {
    const int rj = rj0 + m15;
    const int r = rj >> 1;
    float p = 0.f;
    #pragma unroll
    for (int mt = 0; mt < 4; ++mt)
      #pragma unroll
      for (int reg = 0; reg < 4; ++reg)
        p += acc[mt][reg] * tw[r * 256 + 64 * w + 16 * mt + quad * 4 + reg];
    p += __shfl_xor(p, 16);
    p += __shfl_xor(p, 32);
    if (quad == 0) sred[m15 * 4 + w] = p;
  }
  // W2[rj] = gw_rj . v_b : 16 lanes per rj
  {
    const int oi = tid >> 4, seg = tid & 15;
    const int rj = rj0 + oi;
    float p2 = 0.f;
    #pragma unroll
    for (int i = 0; i < 16; ++i) {
      const int cp = seg * 16 + i;
      p2 += gw[rj * 256 + cp] * V[b * 256 + cp];
    }
    p2 += __shfl_xor(p2, 1);
    p2 += __shfl_xor(p2, 2);
    p2 += __shfl_xor(p2, 4);
    p2 += __shfl_xor(p2, 8);
    if (seg == 0) sred2[oi] = p2;
  }
  __syncthreads();
  if (tid < 16) {
    const int rj = rj0 + tid, r = rj >> 1;
    const float v = sred[tid * 4] + sred[tid * 4 + 1] +
                    sred[tid * 4 + 2] + sred[tid * 4 + 3];
    const float tbr = tb[r];
    const float bias = tbr * sred2[tid] +
                       (U[b * 256 + r] + 4096.0f * tbr) * E[rj] + gb[rj];
    gsh[tid] = fmaxf(v + bias, 0.f);
  }
  __syncthreads();
  // rank-16 update: out[b,c] += sum_i gsh[i] * dw[c, rj0+i]
  float a = 0.f;
  #pragma unroll
  for (int i = 0; i < 16; ++i)
    a += gsh[i] * dw[tid * 512 + rj0 + i];
  atomicAdd(&out[b * 256 + tid], a);
}

extern "C" void kernel_launch(void* const* d_in, const int* in_sizes, int n_in,
                              void* d_out, int out_size, void* d_ws, size_t ws_size,
                              hipStream_t stream) {
  const float* x  = (const float*)d_in[0];
  const float* tw = (const float*)d_in[1];
  const float* tb = (const float*)d_in[2];
  const float* pw = (const float*)d_in[3];
  const float* pb = (const float*)d_in[4];
  const float* gw = (const float*)d_in[5];
  const float* gb = (const float*)d_in[6];
  const float* dw = (const float*)d_in[7];
  const float* db = (const float*)d_in[8];
  float* out = (float*)d_out;

  // workspace: slab 35.7 MB + Gh 2 MB + Qh 0.25 MB + fp32 smalls (~39 MB)
  unsigned short* slab = (unsigned short*)d_ws;                  // 512*136*256
  unsigned short* Gh   = slab + (size_t)KSPLIT * 16 * NPAIR * 256;
  unsigned short* Qh   = Gh + ((size_t)16 << 16);
  float* Spart = (float*)(Qh + 512 * 256);   // 32*16*256
  float* E  = Spart + KSPLIT * 16 * 256;
  float* U  = E + 512;
  float* V  = U + NB * 256;

  k_gram<<<640, 1024, 0, stream>>>(x, slab, Spart, gw, pw, pb, Qh, E);
  k_fuse2<<<592, 256, 0, stream>>>(slab, Spart, pw, tw, db, Gh, U, V, out);
  k_p<<<dim3(32, NB), 256, 0, stream>>>(Gh, Qh, tw, gw, U, V, E, tb, gb, dw, out);
}

// Round 7
// 156.245 us; speedup vs baseline: 1.4014x; 1.4014x over previous
//
#include <hip/hip_runtime.h>

// nonlocal_channel_similarity: B=16, C=256, H=W=64 (N=HW=4096)
//   k_gram : blocks 0..511  : per (ks,b) upper-triangle 16x16 sub-tiles of the
//            partial Gram over K-chunk 128; x read from HBM exactly once.
//            Compact slab (136 tiles * 512 B), coalesced uint2 stores.
//            Row-sum partials -> Spart (plain stores, no atomics).
//            blocks 512..639: Q = gw@Pw (bf16) + E = gw.pb  (overlapped -
//            independent of gram output, runs in its memory shadow).
//   k_fuse2: blocks 0..543: reduce 32 slabs -> bf16 Gh (straight + mirror)
//            blocks 544..575: u = Tw s, v = Pw s   (s = sum of Spart)
//            blocks 576..591: out[b,:] = db  (init for k_p atomics)
//   k_p    : P'' = Gh Qh^T via MFMA; fused term = Tw-contraction + bias +
//            relu; epilogue rank-16 update atomicAdd into out (k_out fused).
//
// NOTE: k_gram MUST stay __launch_bounds__(1024,4). (1024,8) caps VGPR at 32
// and spills the 64-reg accumulator tile to scratch (r6: +150 MB HBM, 99 us).

#define CC  256
#define NB  16
#define HWN 4096
#define KSPLIT 32
#define NPAIR 136   // 16x16 sub-tile pairs (w,ct), ct >= w

typedef __attribute__((ext_vector_type(4))) float f32x4;
typedef __attribute__((ext_vector_type(8))) short bf16x8;

__device__ inline unsigned short f2bf(float f) {
  unsigned u = __float_as_uint(f);
  u += 0x7fff + ((u >> 16) & 1);   // round-to-nearest-even
  return (unsigned short)(u >> 16);
}
__device__ inline float bf2f(unsigned u) { return __uint_as_float(u << 16); }

// ---------------- Gram partials + row-sum partials + Q/E --------------------
// 1D grid 640 blocks, 1024 threads = 16 waves, LDS 64 KB.
// Gram blocks: wave w: A-rows [16w,16w+16), B-tiles ct = w..15 (G symmetric).
// LDS 256x64 bf16 double-buffered, XOR-granule swizzle.
__global__ __launch_bounds__(1024, 4) void k_gram(const float* __restrict__ x,
                                                  unsigned short* __restrict__ slab,
                                                  float* __restrict__ Spart,
                                                  const float* __restrict__ gw,
                                                  const float* __restrict__ pw,
                                                  const float* __restrict__ pb,
                                                  unsigned short* __restrict__ Qh,
                                                  float* __restrict__ E) {
  __shared__ __align__(16) unsigned short As[2][256 * 64];
  const int blk = blockIdx.x, tid = threadIdx.x;

  if (blk >= 512) {
    // ---- Q rows (4 per block) + E: independent of gram, overlapped ----
    const int sub = tid >> 8, t = tid & 255;
    const int rj = (blk - 512) * 4 + sub;
    float* smg = (float*)As + sub * 512;
    smg[t] = gw[rj * 256 + t];
    __syncthreads();
    float q = 0.f;
    for (int p = 0; p < 256; ++p) q += smg[p] * pw[p * 256 + t];
    Qh[rj * 256 + t] = f2bf(q);
    smg[256 + t] = smg[t] * pb[t];
    __syncthreads();
    for (int s = 128; s > 0; s >>= 1) {
      if (t < s) smg[256 + t] += smg[256 + t + s];
      __syncthreads();
    }
    if (t == 0) E[rj] = smg[256];
    return;
  }

  const int ks = blk >> 4, b = blk & 15;
  const float* xb = x + (size_t)b * CC * HWN;

  const int w = tid >> 6, lane = tid & 63;
  const int quad = lane >> 4, m15 = lane & 15;
  const int srow = tid >> 4;                 // 0..63
  const int scol = (tid & 15) << 2;          // 0..60
  const int sg = scol >> 3, so = scol & 7;

  f32x4 acc[16];
  #pragma unroll
  for (int i = 0; i < 16; ++i) acc[i] = (f32x4){0.f, 0.f, 0.f, 0.f};
  float rs[4] = {0.f, 0.f, 0.f, 0.f};

  const int k0 = ks * 128;
  float4 ld[4];
  #pragma unroll
  for (int p = 0; p < 4; ++p)
    ld[p] = *(const float4*)(xb + (size_t)(p * 64 + srow) * HWN + k0 + scol);
  #pragma unroll
  for (int p = 0; p < 4; ++p) {
    const int row = p * 64 + srow;
    rs[p] += ld[p].x + ld[p].y + ld[p].z + ld[p].w;
    *(ushort4*)&As[0][row * 64 + ((sg ^ (row & 7)) << 3) + so] =
        make_ushort4(f2bf(ld[p].x), f2bf(ld[p].y), f2bf(ld[p].z), f2bf(ld[p].w));
  }
  __syncthreads();

  #pragma unroll
  for (int i = 0; i < 2; ++i) {
    if (i < 1) {
      #pragma unroll
      for (int p = 0; p < 4; ++p)
        ld[p] = *(const float4*)(xb + (size_t)(p * 64 + srow) * HWN + k0 + 64 + scol);
    }
    const int rowa = 16 * w + m15;
    #pragma unroll
    for (int kkg = 0; kkg < 8; kkg += 4) {
      const int ga = (kkg + quad) ^ (m15 & 7);
      bf16x8 af = *(const bf16x8*)&As[i][rowa * 64 + ga * 8];
      #pragma unroll
      for (int ct = 0; ct < 16; ++ct) {
        if (ct < w) continue;   // wave-uniform triangle skip
        bf16x8 bfr = *(const bf16x8*)&As[i][(16 * ct + m15) * 64 + ga * 8];
        acc[ct] = __builtin_amdgcn_mfma_f32_16x16x32_bf16(af, bfr, acc[ct], 0, 0, 0);
      }
    }
    if (i < 1) {
      #pragma unroll
      for (int p = 0; p < 4; ++p) {
        const int row = p * 64 + srow;
        rs[p] += ld[p].x + ld[p].y + ld[p].z + ld[p].w;
        *(ushort4*)&As[1][row * 64 + ((sg ^ (row & 7)) << 3) + so] =
            make_ushort4(f2bf(ld[p].x), f2bf(ld[p].y), f2bf(ld[p].z), f2bf(ld[p].w));
      }
    }
    __syncthreads();
  }

  // compact slab: pair (w,ct) -> 512 B tile; lane writes its 4 regs as uint2.
  const int off_w = 16 * w - (w * (w - 1)) / 2;
  unsigned short* sbase = slab + ((size_t)(ks * 16 + b) * NPAIR) * 256;
  #pragma unroll
  for (int ct = 0; ct < 16; ++ct) {
    if (ct < w) continue;
    const int pid = off_w + (ct - w);
    uint2 ov;
    ov.x = (unsigned)f2bf(acc[ct][0]) | ((unsigned)f2bf(acc[ct][1]) << 16);
    ov.y = (unsigned)f2bf(acc[ct][2]) | ((unsigned)f2bf(acc[ct][3]) << 16);
    *(uint2*)(sbase + pid * 256 + lane * 4) = ov;
  }

  #pragma unroll
  for (int p = 0; p < 4; ++p) {
    float v = rs[p];
    v += __shfl_xor(v, 1);
    v += __shfl_xor(v, 2);
    v += __shfl_xor(v, 4);
    v += __shfl_xor(v, 8);
    if ((tid & 15) == 0)
      Spart[(ks * 16 + b) * 256 + p * 64 + srow] = v;
  }
}

// ---------------- fused middle: reduce + u/v + out-init ---------------------
__global__ __launch_bounds__(256) void k_fuse2(const unsigned short* __restrict__ slab,
                                               const float* __restrict__ Spart,
                                               const float* __restrict__ pw,
                                               const float* __restrict__ tw,
                                               const float* __restrict__ db,
                                               unsigned short* __restrict__ Gh,
                                               float* __restrict__ U,
                                               float* __restrict__ V,
                                               float* __restrict__ out) {
  const int blk = blockIdx.x, tid = threadIdx.x;
  if (blk < 544) {
    // slab reduce: thread <-> (b, pair, lane)
    const int t = blk * 256 + tid;          // 0..139263
    const int b = t / 8704;
    const int rem = t % 8704;
    const int pid0 = rem >> 6, lane = rem & 63;
    int w = 0, p = pid0;
    while (p >= 16 - w) { p -= 16 - w; ++w; }
    const int ct = w + p;
    const int quad = lane >> 4, m15 = lane & 15;
    float s[4] = {0.f, 0.f, 0.f, 0.f};
    const unsigned short* sp = slab + (size_t)(b * NPAIR + pid0) * 256 + lane * 4;
    #pragma unroll
    for (int ks = 0; ks < KSPLIT; ++ks) {
      const uint2 v = *(const uint2*)(sp + (size_t)ks * 16 * NPAIR * 256);
      s[0] += bf2f(v.x & 0xffffu); s[1] += bf2f(v.x >> 16);
      s[2] += bf2f(v.y & 0xffffu); s[3] += bf2f(v.y >> 16);
    }
    unsigned short h[4];
    #pragma unroll
    for (int r = 0; r < 4; ++r) h[r] = f2bf(s[r]);
    unsigned short* Gb = Gh + ((size_t)b << 16);
    const int rb = 16 * w + quad * 4;
    const int col = 16 * ct + m15;
    #pragma unroll
    for (int r = 0; r < 4; ++r) Gb[(rb + r) * 256 + col] = h[r];
    // mirror (exact; diagonal overlap writes identical values)
    uint2 mv;
    mv.x = (unsigned)h[0] | ((unsigned)h[1] << 16);
    mv.y = (unsigned)h[2] | ((unsigned)h[3] << 16);
    *(uint2*)(Gb + col * 256 + rb) = mv;
  } else if (blk < 576) {
    // u or v for batch b
    const int m = blk - 544;
    const int b = m & 15, mat = m >> 4;
    const float* Wm = mat ? pw : tw;
    float* outp = mat ? V : U;
    __shared__ float sm[256];
    float sv = 0.f;
    #pragma unroll
    for (int ks = 0; ks < KSPLIT; ++ks)
      sv += Spart[(ks * 16 + b) * 256 + tid];
    sm[tid] = sv;
    __syncthreads();
    const int l = tid & 15, oh = tid >> 4;
    #pragma unroll
    for (int oc = 0; oc < 16; ++oc) {
      const int o = oc * 16 + oh;
      float a = 0.f;
      #pragma unroll
      for (int j = 0; j < 16; ++j)
        a += Wm[o * 256 + l * 16 + j] * sm[l * 16 + j];
      a += __shfl_xor(a, 1);
      a += __shfl_xor(a, 2);
      a += __shfl_xor(a, 4);
      a += __shfl_xor(a, 8);
      if (l == 0) outp[b * 256 + o] = a;
    }
  } else {
    // out init: out[b,:] = db
    const int b = blk - 576;
    out[b * 256 + tid] = db[tid];
  }
}

// ---------------- P'' = Gh Qh^T + fused epilogue (bias/relu + out-update) ---
// grid (32 rj-tiles of 16, 16 b) = 512 blocks (2/CU), 256 thr / 4 waves.
// Wave w: m-rows [64w,64w+64). K = 256. Direct bf16 global loads (L2-hot).
// Epilogue: g (16 values) -> rank-16 atomic update of out[b,:].
__global__ __launch_bounds__(256) void k_p(const unsigned short* __restrict__ Gh,
                                           const unsigned short* __restrict__ Qh,
                                           const float* __restrict__ tw,
                                           const float* __restrict__ gw,
                                           const float* __restrict__ U,
                                           const float* __restrict__ V,
                                           const float* __restrict__ E,
                                           const float* __restrict__ tb,
                                           const float* __restrict__ gb,
                                           const float* __restrict__ dw,
                                           float* __restrict__ out) {
  const int rjt = blockIdx.x, b = blockIdx.y;
  const int rj0 = rjt * 16;
  const int tid = threadIdx.x, w = tid >> 6, lane = tid & 63;
  const int quad = lane >> 4, m15 = lane & 15;
  const unsigned short* Gb = Gh + ((size_t)b << 16);

  f32x4 acc[4];
  #pragma unroll
  for (int mt = 0; mt < 4; ++mt) acc[mt] = (f32x4){0.f, 0.f, 0.f, 0.f};

  #pragma unroll
  for (int s = 0; s < 8; ++s) {
    const int kb = s * 32 + quad * 8;
    bf16x8 bq = *(const bf16x8*)(Qh + (rj0 + m15) * 256 + kb);
    #pragma unroll
    for (int mt = 0; mt < 4; ++mt) {
      bf16x8 ag = *(const bf16x8*)(Gb + (64 * w + 16 * mt + m15) * 256 + kb);
      acc[mt] = __builtin_amdgcn_mfma_f32_16x16x32_bf16(ag, bq, acc[mt], 0, 0, 0);
    }
  }

  // term[rj] = sum_c P''[c,rj]*Tw[r,c]; C/D: col = m15, row = quad*4+reg
  __shared__ float sred[16 * 4];
  __shared__ float sred2[16];
  __shared__ float gsh[16];
  {
    const int rj = rj0 + m15;
    const int r = rj >> 1;
    float p = 0.f;
    #pragma unroll
    for (int mt = 0; mt < 4; ++mt)
      #pragma unroll
      for (int reg = 0; reg < 4; ++reg)
        p += acc[mt][reg] * tw[r * 256 + 64 * w + 16 * mt + quad * 4 + reg];
    p += __shfl_xor(p, 16);
    p += __shfl_xor(p, 32);
    if (quad == 0) sred[m15 * 4 + w] = p;
  }
  // W2[rj] = gw_rj . v_b : 16 lanes per rj
  {
    const int oi = tid >> 4, seg = tid & 15;
    const int rj = rj0 + oi;
    float p2 = 0.f;
    #pragma unroll
    for (int i = 0; i < 16; ++i) {
      const int cp = seg * 16 + i;
      p2 += gw[rj * 256 + cp] * V[b * 256 + cp];
    }
    p2 += __shfl_xor(p2, 1);
    p2 += __shfl_xor(p2, 2);
    p2 += __shfl_xor(p2, 4);
    p2 += __shfl_xor(p2, 8);
    if (seg == 0) sred2[oi] = p2;
  }
  __syncthreads();
  if (tid < 16) {
    const int rj = rj0 + tid, r = rj >> 1;
    const float v = sred[tid * 4] + sred[tid * 4 + 1] +
                    sred[tid * 4 + 2] + sred[tid * 4 + 3];
    const float tbr = tb[r];
    const float bias = tbr * sred2[tid] +
                       (U[b * 256 + r] + 4096.0f * tbr) * E[rj] + gb[rj];
    gsh[tid] = fmaxf(v + bias, 0.f);
  }
  __syncthreads();
  // rank-16 update: out[b,c] += sum_i gsh[i] * dw[c, rj0+i]
  float a = 0.f;
  #pragma unroll
  for (int i = 0; i < 16; ++i)
    a += gsh[i] * dw[tid * 512 + rj0 + i];
  atomicAdd(&out[b * 256 + tid], a);
}

extern "C" void kernel_launch(void* const* d_in, const int* in_sizes, int n_in,
                              void* d_out, int out_size, void* d_ws, size_t ws_size,
                              hipStream_t stream) {
  const float* x  = (const float*)d_in[0];
  const float* tw = (const float*)d_in[1];
  const float* tb = (const float*)d_in[2];
  const float* pw = (const float*)d_in[3];
  const float* pb = (const float*)d_in[4];
  const float* gw = (const float*)d_in[5];
  const float* gb = (const float*)d_in[6];
  const float* dw = (const float*)d_in[7];
  const float* db = (const float*)d_in[8];
  float* out = (float*)d_out;

  // workspace: slab 35.7 MB + Gh 2 MB + Qh 0.25 MB + fp32 smalls (~39 MB)
  unsigned short* slab = (unsigned short*)d_ws;                  // 512*136*256
  unsigned short* Gh   = slab + (size_t)KSPLIT * 16 * NPAIR * 256;
  unsigned short* Qh   = Gh + ((size_t)16 << 16);
  float* Spart = (float*)(Qh + 512 * 256);   // 32*16*256
  float* E  = Spart + KSPLIT * 16 * 256;
  float* U  = E + 512;
  float* V  = U + NB * 256;

  k_gram<<<640, 1024, 0, stream>>>(x, slab, Spart, gw, pw, pb, Qh, E);
  k_fuse2<<<592, 256, 0, stream>>>(slab, Spart, pw, tw, db, Gh, U, V, out);
  k_p<<<dim3(32, NB), 256, 0, stream>>>(Gh, Qh, tw, gw, U, V, E, tb, gb, dw, out);
}

// Round 8
// 154.209 us; speedup vs baseline: 1.4199x; 1.0132x over previous
//
#include <hip/hip_runtime.h>

// nonlocal_channel_similarity: B=16, C=256, H=W=64 (N=HW=4096)
//   k_gram : blocks 0..127  : Q = gw@Pw (bf16) + E = gw.pb (4 rj rows/block,
//            4-way ILP dot; FIRST in dispatch order so they overlap the gram
//            wave instead of forming a tail — r7: tail cost ~30 us).
//            blocks 128..639: per (ks,b) upper-triangle 16x16 sub-tiles of the
//            partial Gram over K-chunk 128; x read from HBM exactly once.
//            Compact slab (136 tiles * 512 B), coalesced uint2 stores.
//            Row-sum partials -> Spart (plain stores, no atomics).
//   k_fuse2: blocks 0..543: reduce 32 slabs -> bf16 Gh (straight + mirror)
//            blocks 544..575: u = Tw s, v = Pw s   (s = sum of Spart)
//            blocks 576..591: out[b,:] = db  (init for k_p atomics)
//   k_p    : P'' = Gh Qh^T via MFMA; fused term = Tw-contraction + bias +
//            relu; epilogue rank-16 update atomicAdd into out.
//
// NOTE: k_gram MUST stay __launch_bounds__(1024,4). (1024,8) caps VGPR at 32
// and spills the 64-reg accumulator tile to scratch (r6: +150 MB HBM, 99 us).

#define CC  256
#define NB  16
#define HWN 4096
#define KSPLIT 32
#define NPAIR 136   // 16x16 sub-tile pairs (w,ct), ct >= w

typedef __attribute__((ext_vector_type(4))) float f32x4;
typedef __attribute__((ext_vector_type(8))) short bf16x8;

__device__ inline unsigned short f2bf(float f) {
  unsigned u = __float_as_uint(f);
  u += 0x7fff + ((u >> 16) & 1);   // round-to-nearest-even
  return (unsigned short)(u >> 16);
}
__device__ inline float bf2f(unsigned u) { return __uint_as_float(u << 16); }

// ---------------- Q/E (blocks 0..127) + Gram partials (128..639) ------------
// 1024 threads = 16 waves, LDS 64 KB -> 2 blocks/CU.
// Gram: wave w: A-rows [16w,16w+16), B-tiles ct = w..15 (G symmetric).
// LDS 256x64 bf16 double-buffered, XOR-granule swizzle.
__global__ __launch_bounds__(1024, 4) void k_gram(const float* __restrict__ x,
                                                  unsigned short* __restrict__ slab,
                                                  float* __restrict__ Spart,
                                                  const float* __restrict__ gw,
                                                  const float* __restrict__ pw,
                                                  const float* __restrict__ pb,
                                                  unsigned short* __restrict__ Qh,
                                                  float* __restrict__ E) {
  __shared__ __align__(16) unsigned short As[2][256 * 64];
  const int blk = blockIdx.x, tid = threadIdx.x;

  if (blk < 128) {
    // ---- Q rows (4 per block) + E; independent of gram, runs first ----
    const int sub = tid >> 8, t = tid & 255;
    const int rj = blk * 4 + sub;
    float* smg = (float*)As + sub * 640;   // 256 gw + 4 wave partials
    smg[t] = gw[rj * 256 + t];
    __syncthreads();
    float q0 = 0.f, q1 = 0.f, q2 = 0.f, q3 = 0.f;
    #pragma unroll 4
    for (int o = 0; o < 256; o += 4) {
      q0 += smg[o]     * pw[o * 256 + t];
      q1 += smg[o + 1] * pw[(o + 1) * 256 + t];
      q2 += smg[o + 2] * pw[(o + 2) * 256 + t];
      q3 += smg[o + 3] * pw[(o + 3) * 256 + t];
    }
    Qh[rj * 256 + t] = f2bf((q0 + q1) + (q2 + q3));
    // E[rj] = sum_t smg[t]*pb[t] : per-wave shuffle reduce + 1 barrier
    float e = smg[t] * pb[t];
    e += __shfl_xor(e, 1);
    e += __shfl_xor(e, 2);
    e += __shfl_xor(e, 4);
    e += __shfl_xor(e, 8);
    e += __shfl_xor(e, 16);
    e += __shfl_xor(e, 32);
    if ((t & 63) == 0) smg[512 + (t >> 6)] = e;
    __syncthreads();
    if (t == 0) E[rj] = smg[512] + smg[513] + smg[514] + smg[515];
    return;
  }

  const int gblk = blk - 128;
  const int ks = gblk >> 4, b = gblk & 15;
  const float* xb = x + (size_t)b * CC * HWN;

  const int w = tid >> 6, lane = tid & 63;
  const int quad = lane >> 4, m15 = lane & 15;
  const int srow = tid >> 4;                 // 0..63
  const int scol = (tid & 15) << 2;          // 0..60
  const int sg = scol >> 3, so = scol & 7;

  f32x4 acc[16];
  #pragma unroll
  for (int i = 0; i < 16; ++i) acc[i] = (f32x4){0.f, 0.f, 0.f, 0.f};
  float rs[4] = {0.f, 0.f, 0.f, 0.f};

  const int k0 = ks * 128;
  float4 ld[4];
  #pragma unroll
  for (int p = 0; p < 4; ++p)
    ld[p] = *(const float4*)(xb + (size_t)(p * 64 + srow) * HWN + k0 + scol);
  #pragma unroll
  for (int p = 0; p < 4; ++p) {
    const int row = p * 64 + srow;
    rs[p] += ld[p].x + ld[p].y + ld[p].z + ld[p].w;
    *(ushort4*)&As[0][row * 64 + ((sg ^ (row & 7)) << 3) + so] =
        make_ushort4(f2bf(ld[p].x), f2bf(ld[p].y), f2bf(ld[p].z), f2bf(ld[p].w));
  }
  __syncthreads();

  #pragma unroll
  for (int i = 0; i < 2; ++i) {
    if (i < 1) {
      #pragma unroll
      for (int p = 0; p < 4; ++p)
        ld[p] = *(const float4*)(xb + (size_t)(p * 64 + srow) * HWN + k0 + 64 + scol);
    }
    const int rowa = 16 * w + m15;
    #pragma unroll
    for (int kkg = 0; kkg < 8; kkg += 4) {
      const int ga = (kkg + quad) ^ (m15 & 7);
      bf16x8 af = *(const bf16x8*)&As[i][rowa * 64 + ga * 8];
      #pragma unroll
      for (int ct = 0; ct < 16; ++ct) {
        if (ct < w) continue;   // wave-uniform triangle skip
        bf16x8 bfr = *(const bf16x8*)&As[i][(16 * ct + m15) * 64 + ga * 8];
        acc[ct] = __builtin_amdgcn_mfma_f32_16x16x32_bf16(af, bfr, acc[ct], 0, 0, 0);
      }
    }
    if (i < 1) {
      #pragma unroll
      for (int p = 0; p < 4; ++p) {
        const int row = p * 64 + srow;
        rs[p] += ld[p].x + ld[p].y + ld[p].z + ld[p].w;
        *(ushort4*)&As[1][row * 64 + ((sg ^ (row & 7)) << 3) + so] =
            make_ushort4(f2bf(ld[p].x), f2bf(ld[p].y), f2bf(ld[p].z), f2bf(ld[p].w));
      }
    }
    __syncthreads();
  }

  // compact slab: pair (w,ct) -> 512 B tile; lane writes its 4 regs as uint2.
  const int off_w = 16 * w - (w * (w - 1)) / 2;
  unsigned short* sbase = slab + ((size_t)(ks * 16 + b) * NPAIR) * 256;
  #pragma unroll
  for (int ct = 0; ct < 16; ++ct) {
    if (ct < w) continue;
    const int pid = off_w + (ct - w);
    uint2 ov;
    ov.x = (unsigned)f2bf(acc[ct][0]) | ((unsigned)f2bf(acc[ct][1]) << 16);
    ov.y = (unsigned)f2bf(acc[ct][2]) | ((unsigned)f2bf(acc[ct][3]) << 16);
    *(uint2*)(sbase + pid * 256 + lane * 4) = ov;
  }

  #pragma unroll
  for (int p = 0; p < 4; ++p) {
    float v = rs[p];
    v += __shfl_xor(v, 1);
    v += __shfl_xor(v, 2);
    v += __shfl_xor(v, 4);
    v += __shfl_xor(v, 8);
    if ((tid & 15) == 0)
      Spart[(ks * 16 + b) * 256 + p * 64 + srow] = v;
  }
}

// ---------------- fused middle: reduce + u/v + out-init ---------------------
__global__ __launch_bounds__(256) void k_fuse2(const unsigned short* __restrict__ slab,
                                               const float* __restrict__ Spart,
                                               const float* __restrict__ pw,
                                               const float* __restrict__ tw,
                                               const float* __restrict__ db,
                                               unsigned short* __restrict__ Gh,
                                               float* __restrict__ U,
                                               float* __restrict__ V,
                                               float* __restrict__ out) {
  const int blk = blockIdx.x, tid = threadIdx.x;
  if (blk < 544) {
    // slab reduce: thread <-> (b, pair, lane)
    const int t = blk * 256 + tid;          // 0..139263
    const int b = t / 8704;
    const int rem = t % 8704;
    const int pid0 = rem >> 6, lane = rem & 63;
    int w = 0, p = pid0;
    while (p >= 16 - w) { p -= 16 - w; ++w; }
    const int ct = w + p;
    const int quad = lane >> 4, m15 = lane & 15;
    float s[4] = {0.f, 0.f, 0.f, 0.f};
    const unsigned short* sp = slab + (size_t)(b * NPAIR + pid0) * 256 + lane * 4;
    #pragma unroll
    for (int ks = 0; ks < KSPLIT; ++ks) {
      const uint2 v = *(const uint2*)(sp + (size_t)ks * 16 * NPAIR * 256);
      s[0] += bf2f(v.x & 0xffffu); s[1] += bf2f(v.x >> 16);
      s[2] += bf2f(v.y & 0xffffu); s[3] += bf2f(v.y >> 16);
    }
    unsigned short h[4];
    #pragma unroll
    for (int r = 0; r < 4; ++r) h[r] = f2bf(s[r]);
    unsigned short* Gb = Gh + ((size_t)b << 16);
    const int rb = 16 * w + quad * 4;
    const int col = 16 * ct + m15;
    #pragma unroll
    for (int r = 0; r < 4; ++r) Gb[(rb + r) * 256 + col] = h[r];
    // mirror (exact; diagonal overlap writes identical values)
    uint2 mv;
    mv.x = (unsigned)h[0] | ((unsigned)h[1] << 16);
    mv.y = (unsigned)h[2] | ((unsigned)h[3] << 16);
    *(uint2*)(Gb + col * 256 + rb) = mv;
  } else if (blk < 576) {
    // u or v for batch b
    const int m = blk - 544;
    const int b = m & 15, mat = m >> 4;
    const float* Wm = mat ? pw : tw;
    float* outp = mat ? V : U;
    __shared__ float sm[256];
    float sv = 0.f;
    #pragma unroll
    for (int ks = 0; ks < KSPLIT; ++ks)
      sv += Spart[(ks * 16 + b) * 256 + tid];
    sm[tid] = sv;
    __syncthreads();
    const int l = tid & 15, oh = tid >> 4;
    #pragma unroll
    for (int oc = 0; oc < 16; ++oc) {
      const int o = oc * 16 + oh;
      float a = 0.f;
      #pragma unroll
      for (int j = 0; j < 16; ++j)
        a += Wm[o * 256 + l * 16 + j] * sm[l * 16 + j];
      a += __shfl_xor(a, 1);
      a += __shfl_xor(a, 2);
      a += __shfl_xor(a, 4);
      a += __shfl_xor(a, 8);
      if (l == 0) outp[b * 256 + o] = a;
    }
  } else {
    // out init: out[b,:] = db
    const int b = blk - 576;
    out[b * 256 + tid] = db[tid];
  }
}

// ---------------- P'' = Gh Qh^T + fused epilogue (bias/relu + out-update) ---
// grid (32 rj-tiles of 16, 16 b) = 512 blocks (2/CU), 256 thr / 4 waves.
// Wave w: m-rows [64w,64w+64). K = 256. Direct bf16 global loads (L2-hot).
// Epilogue: g (16 values) -> rank-16 atomic update of out[b,:].
__global__ __launch_bounds__(256) void k_p(const unsigned short* __restrict__ Gh,
                                           const unsigned short* __restrict__ Qh,
                                           const float* __restrict__ tw,
                                           const float* __restrict__ gw,
                                           const float* __restrict__ U,
                                           const float* __restrict__ V,
                                           const float* __restrict__ E,
                                           const float* __restrict__ tb,
                                           const float* __restrict__ gb,
                                           const float* __restrict__ dw,
                                           float* __restrict__ out) {
  const int rjt = blockIdx.x, b = blockIdx.y;
  const int rj0 = rjt * 16;
  const int tid = threadIdx.x, w = tid >> 6, lane = tid & 63;
  const int quad = lane >> 4, m15 = lane & 15;
  const unsigned short* Gb = Gh + ((size_t)b << 16);

  f32x4 acc[4];
  #pragma unroll
  for (int mt = 0; mt < 4; ++mt) acc[mt] = (f32x4){0.f, 0.f, 0.f, 0.f};

  #pragma unroll
  for (int s = 0; s < 8; ++s) {
    const int kb = s * 32 + quad * 8;
    bf16x8 bq = *(const bf16x8*)(Qh + (rj0 + m15) * 256 + kb);
    #pragma unroll
    for (int mt = 0; mt < 4; ++mt) {
      bf16x8 ag = *(const bf16x8*)(Gb + (64 * w + 16 * mt + m15) * 256 + kb);
      acc[mt] = __builtin_amdgcn_mfma_f32_16x16x32_bf16(ag, bq, acc[mt], 0, 0, 0);
    }
  }

  // term[rj] = sum_c P''[c,rj]*Tw[r,c]; C/D: col = m15, row = quad*4+reg
  __shared__ float sred[16 * 4];
  __shared__ float sred2[16];
  __shared__ float gsh[16];
  {
    const int rj = rj0 + m15;
    const int r = rj >> 1;
    float p = 0.f;
    #pragma unroll
    for (int mt = 0; mt < 4; ++mt)
      #pragma unroll
      for (int reg = 0; reg < 4; ++reg)
        p += acc[mt][reg] * tw[r * 256 + 64 * w + 16 * mt + quad * 4 + reg];
    p += __shfl_xor(p, 16);
    p += __shfl_xor(p, 32);
    if (quad == 0) sred[m15 * 4 + w] = p;
  }
  // W2[rj] = gw_rj . v_b : 16 lanes per rj
  {
    const int oi = tid >> 4, seg = tid & 15;
    const int rj = rj0 + oi;
    float p2 = 0.f;
    #pragma unroll
    for (int i = 0; i < 16; ++i) {
      const int cp = seg * 16 + i;
      p2 += gw[rj * 256 + cp] * V[b * 256 + cp];
    }
    p2 += __shfl_xor(p2, 1);
    p2 += __shfl_xor(p2, 2);
    p2 += __shfl_xor(p2, 4);
    p2 += __shfl_xor(p2, 8);
    if (seg == 0) sred2[oi] = p2;
  }
  __syncthreads();
  if (tid < 16) {
    const int rj = rj0 + tid, r = rj >> 1;
    const float v = sred[tid * 4] + sred[tid * 4 + 1] +
                    sred[tid * 4 + 2] + sred[tid * 4 + 3];
    const float tbr = tb[r];
    const float bias = tbr * sred2[tid] +
                       (U[b * 256 + r] + 4096.0f * tbr) * E[rj] + gb[rj];
    gsh[tid] = fmaxf(v + bias, 0.f);
  }
  __syncthreads();
  // rank-16 update: out[b,c] += sum_i gsh[i] * dw[c, rj0+i]
  float a = 0.f;
  #pragma unroll
  for (int i = 0; i < 16; ++i)
    a += gsh[i] * dw[tid * 512 + rj0 + i];
  atomicAdd(&out[b * 256 + tid], a);
}

extern "C" void kernel_launch(void* const* d_in, const int* in_sizes, int n_in,
                              void* d_out, int out_size, void* d_ws, size_t ws_size,
                              hipStream_t stream) {
  const float* x  = (const float*)d_in[0];
  const float* tw = (const float*)d_in[1];
  const float* tb = (const float*)d_in[2];
  const float* pw = (const float*)d_in[3];
  const float* pb = (const float*)d_in[4];
  const float* gw = (const float*)d_in[5];
  const float* gb = (const float*)d_in[6];
  const float* dw = (const float*)d_in[7];
  const float* db = (const float*)d_in[8];
  float* out = (float*)d_out;

  // workspace: slab 35.7 MB + Gh 2 MB + Qh 0.25 MB + fp32 smalls (~39 MB)
  unsigned short* slab = (unsigned short*)d_ws;                  // 512*136*256
  unsigned short* Gh   = slab + (size_t)KSPLIT * 16 * NPAIR * 256;
  unsigned short* Qh   = Gh + ((size_t)16 << 16);
  float* Spart = (float*)(Qh + 512 * 256);   // 32*16*256
  float* E  = Spart + KSPLIT * 16 * 256;
  float* U  = E + 512;
  float* V  = U + NB * 256;

  k_gram<<<640, 1024, 0, stream>>>(x, slab, Spart, gw, pw, pb, Qh, E);
  k_fuse2<<<592, 256, 0, stream>>>(slab, Spart, pw, tw, db, Gh, U, V, out);
  k_p<<<dim3(32, NB), 256, 0, stream>>>(Gh, Qh, tw, gw, U, V, E, tb, gb, dw, out);
}

// Round 9
// 147.565 us; speedup vs baseline: 1.4839x; 1.0450x over previous
//
#include <hip/hip_runtime.h>

// nonlocal_channel_similarity: B=16, C=256, H=W=64 (N=HW=4096)
//   k_gram : 256 blocks (16 ks x 16 b) = EXACTLY 1 block/CU, one round.
//            (reg arithmetic: wave0 carries 16 acc tiles = 64 AGPR + ~60 VGPR
//             ~ 124 regs/lane -> 16 waves/CU -> 1 block/CU. Any grid > 256
//             serializes in rounds: r7/r8's 640-block grid = 2.5 rounds = 40us.)
//            Per block: upper-triangle 16x16 sub-tiles of partial Gram over
//            K-chunk 256 (4 x 64-col double-buffered LDS sub-chunks); x read
//            from HBM exactly once. Compact slab (136 tiles * 512 B, uint2
//            stores). Row-sum partials -> Spart.
//   k_fuse2: blocks 0..543   : reduce 16 slabs -> bf16 Gh (straight + mirror)
//            blocks 544..1055: Q = gw@Pw (bf16) + E = gw.pb (1 rj row/block)
//            blocks 1056..1087: u = Tw s, v = Pw s  (s = sum of Spart)
//            blocks 1088..1103: out[b,:] = db  (init for k_p atomics)
//   k_p    : P'' = Gh Qh^T via MFMA; fused term = Tw-contraction + bias +
//            relu; epilogue rank-16 update atomicAdd into out.
//
// NOTE: k_gram MUST stay __launch_bounds__(1024,4). (1024,8) caps regs at 64
// total and spills the 64-reg accumulator tile to scratch (r6: +150 MB HBM).

#define CC  256
#define NB  16
#define HWN 4096
#define KSPLIT 16
#define NPAIR 136   // 16x16 sub-tile pairs (w,ct), ct >= w

typedef __attribute__((ext_vector_type(4))) float f32x4;
typedef __attribute__((ext_vector_type(8))) short bf16x8;

__device__ inline unsigned short f2bf(float f) {
  unsigned u = __float_as_uint(f);
  u += 0x7fff + ((u >> 16) & 1);   // round-to-nearest-even
  return (unsigned short)(u >> 16);
}
__device__ inline float bf2f(unsigned u) { return __uint_as_float(u << 16); }

// ---------------- Gram partials + row-sum partials --------------------------
// 256 blocks, 1024 threads = 16 waves, LDS 64 KB (dbuf 2 x 256x64 bf16).
// Wave w: A-rows [16w,16w+16), B-tiles ct = w..15 (G symmetric).
// XOR-granule swizzle keeps b128 frag reads conflict-free.
__global__ __launch_bounds__(1024, 4) void k_gram(const float* __restrict__ x,
                                                  unsigned short* __restrict__ slab,
                                                  float* __restrict__ Spart) {
  __shared__ __align__(16) unsigned short As[2][256 * 64];
  const int blk = blockIdx.x, tid = threadIdx.x;
  const int ks = blk >> 4, b = blk & 15;
  const float* xb = x + (size_t)b * CC * HWN;

  const int w = tid >> 6, lane = tid & 63;
  const int quad = lane >> 4, m15 = lane & 15;
  const int srow = tid >> 4;                 // 0..63
  const int scol = (tid & 15) << 2;          // 0..60
  const int sg = scol >> 3, so = scol & 7;

  f32x4 acc[16];
  #pragma unroll
  for (int i = 0; i < 16; ++i) acc[i] = (f32x4){0.f, 0.f, 0.f, 0.f};
  float rs[4] = {0.f, 0.f, 0.f, 0.f};

  const int k0 = ks * 256;
  float4 ld[4];
  #pragma unroll
  for (int p = 0; p < 4; ++p)
    ld[p] = *(const float4*)(xb + (size_t)(p * 64 + srow) * HWN + k0 + scol);
  #pragma unroll
  for (int p = 0; p < 4; ++p) {
    const int row = p * 64 + srow;
    rs[p] += ld[p].x + ld[p].y + ld[p].z + ld[p].w;
    *(ushort4*)&As[0][row * 64 + ((sg ^ (row & 7)) << 3) + so] =
        make_ushort4(f2bf(ld[p].x), f2bf(ld[p].y), f2bf(ld[p].z), f2bf(ld[p].w));
  }
  __syncthreads();

  #pragma unroll
  for (int i = 0; i < 4; ++i) {
    const int cur = i & 1;
    if (i < 3) {
      const int kc = k0 + (i + 1) * 64;
      #pragma unroll
      for (int p = 0; p < 4; ++p)
        ld[p] = *(const float4*)(xb + (size_t)(p * 64 + srow) * HWN + kc + scol);
    }
    const int rowa = 16 * w + m15;
    #pragma unroll
    for (int kkg = 0; kkg < 8; kkg += 4) {
      const int ga = (kkg + quad) ^ (m15 & 7);
      bf16x8 af = *(const bf16x8*)&As[cur][rowa * 64 + ga * 8];
      #pragma unroll
      for (int ct = 0; ct < 16; ++ct) {
        if (ct < w) continue;   // wave-uniform triangle skip
        bf16x8 bfr = *(const bf16x8*)&As[cur][(16 * ct + m15) * 64 + ga * 8];
        acc[ct] = __builtin_amdgcn_mfma_f32_16x16x32_bf16(af, bfr, acc[ct], 0, 0, 0);
      }
    }
    if (i < 3) {
      #pragma unroll
      for (int p = 0; p < 4; ++p) {
        const int row = p * 64 + srow;
        rs[p] += ld[p].x + ld[p].y + ld[p].z + ld[p].w;
        *(ushort4*)&As[1 - cur][row * 64 + ((sg ^ (row & 7)) << 3) + so] =
            make_ushort4(f2bf(ld[p].x), f2bf(ld[p].y), f2bf(ld[p].z), f2bf(ld[p].w));
      }
    }
    __syncthreads();
  }

  // compact slab: pair (w,ct) -> 512 B tile; lane writes its 4 regs as uint2.
  const int off_w = 16 * w - (w * (w - 1)) / 2;
  unsigned short* sbase = slab + ((size_t)(ks * 16 + b) * NPAIR) * 256;
  #pragma unroll
  for (int ct = 0; ct < 16; ++ct) {
    if (ct < w) continue;
    const int pid = off_w + (ct - w);
    uint2 ov;
    ov.x = (unsigned)f2bf(acc[ct][0]) | ((unsigned)f2bf(acc[ct][1]) << 16);
    ov.y = (unsigned)f2bf(acc[ct][2]) | ((unsigned)f2bf(acc[ct][3]) << 16);
    *(uint2*)(sbase + pid * 256 + lane * 4) = ov;
  }

  #pragma unroll
  for (int p = 0; p < 4; ++p) {
    float v = rs[p];
    v += __shfl_xor(v, 1);
    v += __shfl_xor(v, 2);
    v += __shfl_xor(v, 4);
    v += __shfl_xor(v, 8);
    if ((tid & 15) == 0)
      Spart[(ks * 16 + b) * 256 + p * 64 + srow] = v;
  }
}

// ---------------- fused middle: reduce + Q/E + u/v + out-init ---------------
__global__ __launch_bounds__(256) void k_fuse2(const unsigned short* __restrict__ slab,
                                               const float* __restrict__ Spart,
                                               const float* __restrict__ gw,
                                               const float* __restrict__ pw,
                                               const float* __restrict__ pb,
                                               const float* __restrict__ tw,
                                               const float* __restrict__ db,
                                               unsigned short* __restrict__ Gh,
                                               unsigned short* __restrict__ Qh,
                                               float* __restrict__ E,
                                               float* __restrict__ U,
                                               float* __restrict__ V,
                                               float* __restrict__ out) {
  const int blk = blockIdx.x, tid = threadIdx.x;
  if (blk < 544) {
    // slab reduce: thread <-> (b, pair, lane)
    const int t = blk * 256 + tid;          // 0..139263
    const int b = t / 8704;
    const int rem = t % 8704;
    const int pid0 = rem >> 6, lane = rem & 63;
    int w = 0, p = pid0;
    while (p >= 16 - w) { p -= 16 - w; ++w; }
    const int ct = w + p;
    const int quad = lane >> 4, m15 = lane & 15;
    float s[4] = {0.f, 0.f, 0.f, 0.f};
    const unsigned short* sp = slab + (size_t)(b * NPAIR + pid0) * 256 + lane * 4;
    #pragma unroll
    for (int ks = 0; ks < KSPLIT; ++ks) {
      const uint2 v = *(const uint2*)(sp + (size_t)ks * 16 * NPAIR * 256);
      s[0] += bf2f(v.x & 0xffffu); s[1] += bf2f(v.x >> 16);
      s[2] += bf2f(v.y & 0xffffu); s[3] += bf2f(v.y >> 16);
    }
    unsigned short h[4];
    #pragma unroll
    for (int r = 0; r < 4; ++r) h[r] = f2bf(s[r]);
    unsigned short* Gb = Gh + ((size_t)b << 16);
    const int rb = 16 * w + quad * 4;
    const int col = 16 * ct + m15;
    #pragma unroll
    for (int r = 0; r < 4; ++r) Gb[(rb + r) * 256 + col] = h[r];
    // mirror (exact; diagonal overlap writes identical values)
    uint2 mv;
    mv.x = (unsigned)h[0] | ((unsigned)h[1] << 16);
    mv.y = (unsigned)h[2] | ((unsigned)h[3] << 16);
    *(uint2*)(Gb + col * 256 + rb) = mv;
  } else if (blk < 1056) {
    // Q row rj (bf16) + E[rj], 4-way ILP dot
    const int rj = blk - 544;
    __shared__ float smg[260];
    smg[tid] = gw[rj * 256 + tid];
    __syncthreads();
    float q0 = 0.f, q1 = 0.f, q2 = 0.f, q3 = 0.f;
    #pragma unroll 4
    for (int o = 0; o < 256; o += 4) {
      q0 += smg[o]     * pw[o * 256 + tid];
      q1 += smg[o + 1] * pw[(o + 1) * 256 + tid];
      q2 += smg[o + 2] * pw[(o + 2) * 256 + tid];
      q3 += smg[o + 3] * pw[(o + 3) * 256 + tid];
    }
    Qh[rj * 256 + tid] = f2bf((q0 + q1) + (q2 + q3));
    float e = smg[tid] * pb[tid];
    e += __shfl_xor(e, 1);
    e += __shfl_xor(e, 2);
    e += __shfl_xor(e, 4);
    e += __shfl_xor(e, 8);
    e += __shfl_xor(e, 16);
    e += __shfl_xor(e, 32);
    if ((tid & 63) == 0) smg[256 + (tid >> 6)] = e;
    __syncthreads();
    if (tid == 0) E[rj] = smg[256] + smg[257] + smg[258] + smg[259];
  } else if (blk < 1088) {
    // u or v for batch b
    const int m = blk - 1056;
    const int b = m & 15, mat = m >> 4;
    const float* Wm = mat ? pw : tw;
    float* outp = mat ? V : U;
    __shared__ float sm[256];
    float sv = 0.f;
    #pragma unroll
    for (int ks = 0; ks < KSPLIT; ++ks)
      sv += Spart[(ks * 16 + b) * 256 + tid];
    sm[tid] = sv;
    __syncthreads();
    const int l = tid & 15, oh = tid >> 4;
    #pragma unroll
    for (int oc = 0; oc < 16; ++oc) {
      const int o = oc * 16 + oh;
      float a = 0.f;
      #pragma unroll
      for (int j = 0; j < 16; ++j)
        a += Wm[o * 256 + l * 16 + j] * sm[l * 16 + j];
      a += __shfl_xor(a, 1);
      a += __shfl_xor(a, 2);
      a += __shfl_xor(a, 4);
      a += __shfl_xor(a, 8);
      if (l == 0) outp[b * 256 + o] = a;
    }
  } else {
    // out init: out[b,:] = db
    const int b = blk - 1088;
    out[b * 256 + tid] = db[tid];
  }
}

// ---------------- P'' = Gh Qh^T + fused epilogue (bias/relu + out-update) ---
// grid (32 rj-tiles of 16, 16 b) = 512 blocks, 256 thr / 4 waves.
// Wave w: m-rows [64w,64w+64). K = 256. Direct bf16 global loads (L2-hot).
// Epilogue: g (16 values) -> rank-16 atomic update of out[b,:].
__global__ __launch_bounds__(256) void k_p(const unsigned short* __restrict__ Gh,
                                           const unsigned short* __restrict__ Qh,
                                           const float* __restrict__ tw,
                                           const float* __restrict__ gw,
                                           const float* __restrict__ U,
                                           const float* __restrict__ V,
                                           const float* __restrict__ E,
                                           const float* __restrict__ tb,
                                           const float* __restrict__ gb,
                                           const float* __restrict__ dw,
                                           float* __restrict__ out) {
  const int rjt = blockIdx.x, b = blockIdx.y;
  const int rj0 = rjt * 16;
  const int tid = threadIdx.x, w = tid >> 6, lane = tid & 63;
  const int quad = lane >> 4, m15 = lane & 15;
  const unsigned short* Gb = Gh + ((size_t)b << 16);

  f32x4 acc[4];
  #pragma unroll
  for (int mt = 0; mt < 4; ++mt) acc[mt] = (f32x4){0.f, 0.f, 0.f, 0.f};

  #pragma unroll
  for (int s = 0; s < 8; ++s) {
    const int kb = s * 32 + quad * 8;
    bf16x8 bq = *(const bf16x8*)(Qh + (rj0 + m15) * 256 + kb);
    #pragma unroll
    for (int mt = 0; mt < 4; ++mt) {
      bf16x8 ag = *(const bf16x8*)(Gb + (64 * w + 16 * mt + m15) * 256 + kb);
      acc[mt] = __builtin_amdgcn_mfma_f32_16x16x32_bf16(ag, bq, acc[mt], 0, 0, 0);
    }
  }

  // term[rj] = sum_c P''[c,rj]*Tw[r,c]; C/D: col = m15, row = quad*4+reg
  __shared__ float sred[16 * 4];
  __shared__ float sred2[16];
  __shared__ float gsh[16];
  {
    const int rj = rj0 + m15;
    const int r = rj >> 1;
    float p = 0.f;
    #pragma unroll
    for (int mt = 0; mt < 4; ++mt)
      #pragma unroll
      for (int reg = 0; reg < 4; ++reg)
        p += acc[mt][reg] * tw[r * 256 + 64 * w + 16 * mt + quad * 4 + reg];
    p += __shfl_xor(p, 16);
    p += __shfl_xor(p, 32);
    if (quad == 0) sred[m15 * 4 + w] = p;
  }
  // W2[rj] = gw_rj . v_b : 16 lanes per rj
  {
    const int oi = tid >> 4, seg = tid & 15;
    const int rj = rj0 + oi;
    float p2 = 0.f;
    #pragma unroll
    for (int i = 0; i < 16; ++i) {
      const int cp = seg * 16 + i;
      p2 += gw[rj * 256 + cp] * V[b * 256 + cp];
    }
    p2 += __shfl_xor(p2, 1);
    p2 += __shfl_xor(p2, 2);
    p2 += __shfl_xor(p2, 4);
    p2 += __shfl_xor(p2, 8);
    if (seg == 0) sred2[oi] = p2;
  }
  __syncthreads();
  if (tid < 16) {
    const int rj = rj0 + tid, r = rj >> 1;
    const float v = sred[tid * 4] + sred[tid * 4 + 1] +
                    sred[tid * 4 + 2] + sred[tid * 4 + 3];
    const float tbr = tb[r];
    const float bias = tbr * sred2[tid] +
                       (U[b * 256 + r] + 4096.0f * tbr) * E[rj] + gb[rj];
    gsh[tid] = fmaxf(v + bias, 0.f);
  }
  __syncthreads();
  // rank-16 update: out[b,c] += sum_i gsh[i] * dw[c, rj0+i]
  float a = 0.f;
  #pragma unroll
  for (int i = 0; i < 16; ++i)
    a += gsh[i] * dw[tid * 512 + rj0 + i];
  atomicAdd(&out[b * 256 + tid], a);
}

extern "C" void kernel_launch(void* const* d_in, const int* in_sizes, int n_in,
                              void* d_out, int out_size, void* d_ws, size_t ws_size,
                              hipStream_t stream) {
  const float* x  = (const float*)d_in[0];
  const float* tw = (const float*)d_in[1];
  const float* tb = (const float*)d_in[2];
  const float* pw = (const float*)d_in[3];
  const float* pb = (const float*)d_in[4];
  const float* gw = (const float*)d_in[5];
  const float* gb = (const float*)d_in[6];
  const float* dw = (const float*)d_in[7];
  const float* db = (const float*)d_in[8];
  float* out = (float*)d_out;

  // workspace: slab 17.8 MB + Gh 2 MB + Qh 0.25 MB + fp32 smalls (~21 MB)
  unsigned short* slab = (unsigned short*)d_ws;                  // 256*136*256
  unsigned short* Gh   = slab + (size_t)KSPLIT * 16 * NPAIR * 256;
  unsigned short* Qh   = Gh + ((size_t)16 << 16);
  float* Spart = (float*)(Qh + 512 * 256);   // 16*16*256
  float* E  = Spart + KSPLIT * 16 * 256;
  float* U  = E + 512;
  float* V  = U + NB * 256;

  k_gram<<<256, 1024, 0, stream>>>(x, slab, Spart);
  k_fuse2<<<1104, 256, 0, stream>>>(slab, Spart, gw, pw, pb, tw, db,
                                    Gh, Qh, E, U, V, out);
  k_p<<<dim3(32, NB), 256, 0, stream>>>(Gh, Qh, tw, gw, U, V, E, tb, gb, dw, out);
}